// Round 7
// baseline (573.435 us; speedup 1.0000x reference)
//
#include <hip/hip_runtime.h>
#include <hip/hip_bf16.h>

typedef short short8 __attribute__((ext_vector_type(8)));
typedef float f32x4  __attribute__((ext_vector_type(4)));
typedef unsigned int u32;

#define EMB   512
#define MEM   128
#define G3    384
#define CLS_K 640
#define MSPLIT 8
#define MSL   16              // m-columns per block (one 16-wide MFMA tile)
#define BR    256             // rows per block (8 waves x 32)
#define NTHR  512
#define NSLICE (MSPLIT + 1)   // logit partial slices (8 mem + 1 emb)

#define W1ROWS (3 * MSL)          // 48
#define SWIH_E (W1ROWS * EMB)     // 24576 shorts
#define SWHH_E (W1ROWS * MEM)     // 6144 shorts
#define SWCL_E (2 * EMB)          // 1024 shorts

__device__ __forceinline__ short f2b(float f) {
  __hip_bfloat16 h = __float2bfloat16(f);
  return __builtin_bit_cast(short, h);
}
__device__ __forceinline__ short8 cvt8(f32x4 a, f32x4 b) {
  short8 v;
  v[0] = f2b(a[0]); v[1] = f2b(a[1]); v[2] = f2b(a[2]); v[3] = f2b(a[3]);
  v[4] = f2b(b[0]); v[5] = f2b(b[1]); v[6] = f2b(b[2]); v[7] = f2b(b[3]);
  return v;
}
__device__ __forceinline__ float sigm(float x)     { return 1.f / (1.f + __expf(-x)); }
__device__ __forceinline__ float tanhfast(float x) { return 2.f / (1.f + __expf(-2.f * x)) - 1.f; }

// swizzled LDS access: spreads same-column reads across 8 16B slots
__device__ __forceinline__ short8 ldsW(const short* base, int rowBytes, int r, int kb) {
  const int byte = (r * rowBytes + kb) ^ ((r & 7) << 4);
  return *(const short8*)((const char*)base + byte);
}
__device__ __forceinline__ void stsW(short* base, int rowBytes, int r, int kb, short8 v) {
  const int byte = (r * rowBytes + kb) ^ ((r & 7) << 4);
  *(short8*)((char*)base + byte) = v;
}

// ---- convert all weights to bf16 in workspace ----
__global__ void prep_w_kernel(const float* __restrict__ wih, const float* __restrict__ whh,
                              const float* __restrict__ wcls, short* __restrict__ outw) {
  int i = blockIdx.x * blockDim.x + threadIdx.x;
  const int n1 = G3 * EMB;
  const int n2 = n1 + G3 * MEM;
  const int n3 = n2 + 2 * CLS_K;
  if (i < n1) outw[i] = f2b(wih[i]);
  else if (i < n2) outw[i] = f2b(whh[i - n1]);
  else if (i < n3) outw[i] = f2b(wcls[i - n2]);
}

__global__ void zero_kernel(float* __restrict__ lg, int nlg) {
  int i = blockIdx.x * blockDim.x + threadIdx.x;
  if (i < nlg) lg[i] = 0.f;
}

__global__ void bitmap_set_kernel(const int* __restrict__ ids, unsigned char* __restrict__ bm, int n) {
  int i = blockIdx.x * blockDim.x + threadIdx.x;
  if (i < n) bm[ids[i]] = 1;
}

// ---- bank copy; skips rows the scatter wrote (bm!=null) ----
__global__ void copy_bank_kernel(const f32x4* __restrict__ src, f32x4* __restrict__ dst,
                                 const unsigned char* __restrict__ bm, int n4) {
  int i = blockIdx.x * blockDim.x + threadIdx.x;
  int stride = gridDim.x * blockDim.x;
  for (; i < n4; i += stride) {
    if (bm && bm[i >> 5]) continue;    // MEM/4 = 32 chunks per row
    dst[i] = src[i];
  }
}

// ---- final logit reduce: out[i] = bcls[i&1] + sum over NSLICE partial slices ----
__global__ void reduce_logits_kernel(const float* __restrict__ part, const float* __restrict__ bcls,
                                     float* __restrict__ out, int n2) {
  int i = blockIdx.x * blockDim.x + threadIdx.x;
  if (i < n2) {
    float s = bcls[i & 1];
#pragma unroll
    for (int sl = 0; sl < NSLICE; ++sl) s += part[(size_t)sl * n2 + i];
    out[i] = s;
  }
}

template <bool BF16W, bool PARTIALS>
__global__ __launch_bounds__(NTHR, 4)
void fused_gru_kernel(const float* __restrict__ emb, const int* __restrict__ ids,
                      const float* __restrict__ bank,
                      const float* __restrict__ Wihf, const float* __restrict__ Whhf,
                      const float* __restrict__ bih,  const float* __restrict__ bhh,
                      const float* __restrict__ Wcls, const float* __restrict__ bcls,
                      const short* __restrict__ Wb,   float* __restrict__ part,
                      float* __restrict__ out_logits, float* __restrict__ out_bank, int N) {
  __shared__ __align__(16) short sW[SWIH_E + SWHH_E + SWCL_E];   // 63.5 KB -> 2 blocks/CU
  short* sWih = sW;
  short* sWhh = sW + SWIH_E;
  short* sWcl = sW + SWIH_E + SWHH_E;

  const int t = threadIdx.x;

  // ---- block remap: all 8 m-slices of a row-group on the same XCD, dispatched together ----
  const int nrb   = (N + BR - 1) / BR;
  const int full  = nrb & ~7;
  const int nfull = full * MSPLIT;
  int rg, ms;
  {
    const int bi = blockIdx.x;
    if (bi < nfull) { rg = (bi & 7) + ((bi >> 6) << 3); ms = (bi >> 3) & 7; }
    else            { const int r = bi - nfull, rem = nrb - full; rg = full + r % rem; ms = r / rem; }
  }
  const bool ms0 = (ms == 0);
  const int r0 = rg * BR;

  // ---------------- per-wave setup + early gather issue ----------------
  const int w    = t >> 6;          // 0..7, wave owns rows [w*32, w*32+32)
  const int l    = t & 63;
  const int lr   = l & 15;
  const int lk   = l >> 4;
  const int wrow = w * 32;

  int grow0 = r0 + wrow + lr;      if (grow0 > N - 1) grow0 = N - 1;
  int grow1 = r0 + wrow + 16 + lr; if (grow1 > N - 1) grow1 = N - 1;
  const int gid0 = ids[grow0];
  const int gid1 = ids[grow1];

  const float* x0 = emb  + (size_t)grow0 * EMB + lk * 8;
  const float* x1 = emb  + (size_t)grow1 * EMB + lk * 8;
  const float* h0 = bank + (size_t)gid0 * MEM + lk * 8;
  const float* h1 = bank + (size_t)gid1 * MEM + lk * 8;

  // depth-4 rotating prefetch stages; issued before weight staging
  f32x4 pa[4][2], pb[4][2];         // [stage][row]
#pragma unroll
  for (int s = 0; s < 4; ++s) {
    pa[s][0] = *(const f32x4*)(x0 + s * 32); pb[s][0] = *(const f32x4*)(x0 + s * 32 + 4);
    pa[s][1] = *(const f32x4*)(x1 + s * 32); pb[s][1] = *(const f32x4*)(x1 + s * 32 + 4);
  }

  // bias / classifier scalars (hidden under staging)
  const int m = ms * MSL + lr;
  const float wcm0 = Wcls[EMB + m];
  const float wcm1 = Wcls[CLS_K + EMB + m];
  const float bir = bih[m]           + bhh[m];
  const float biz = bih[MEM + m]     + bhh[MEM + m];
  const float bin_ = bih[2 * MEM + m];
  const float bhn  = bhh[2 * MEM + m];

  const short* Wihb = Wb;
  const short* Whhb = Wb + G3 * EMB;
  const short* Wclb = Wb + G3 * EMB + G3 * MEM;

  // ---------------- stage weight slices into swizzled LDS ----------------
  // local row r in [0,48): gate g=r/16, mloc=r%16 -> global row g*128 + ms*16 + mloc
#pragma unroll
  for (int i = 0; i < 6; ++i) {                     // W_ih: 3072 16B chunks
    const int c = t + i * NTHR;
    const int r = c >> 6, k8 = c & 63;
    const int grow = (r >> 4) * MEM + ms * MSL + (r & 15);
    short8 v;
    if constexpr (BF16W) v = *(const short8*)(Wihb + (size_t)grow * EMB + k8 * 8);
    else {
      const float* p = Wihf + (size_t)grow * EMB + k8 * 8;
      v = cvt8(*(const f32x4*)p, *(const f32x4*)(p + 4));
    }
    stsW(sWih, EMB * 2, r, k8 * 16, v);
  }
#pragma unroll
  for (int i = 0; i < 2; ++i) {                     // W_hh: 768 16B chunks
    const int c = t + i * NTHR;
    if (c < W1ROWS * 16) {
      const int r = c >> 4, k8 = c & 15;
      const int grow = (r >> 4) * MEM + ms * MSL + (r & 15);
      short8 v;
      if constexpr (BF16W) v = *(const short8*)(Whhb + (size_t)grow * MEM + k8 * 8);
      else {
        const float* p = Whhf + (size_t)grow * MEM + k8 * 8;
        v = cvt8(*(const f32x4*)p, *(const f32x4*)(p + 4));
      }
      stsW(sWhh, MEM * 2, r, k8 * 16, v);
    }
  }
  if (t < 128) {                                    // W_cls emb-part: 2 rows x 512
    const int r = t >> 6, k8 = t & 63;
    short8 v;
    if constexpr (BF16W) v = *(const short8*)(Wclb + (size_t)r * CLS_K + k8 * 8);
    else {
      const float* p = Wcls + (size_t)r * CLS_K + k8 * 8;
      v = cvt8(*(const f32x4*)p, *(const f32x4*)(p + 4));
    }
    stsW(sWcl, EMB * 2, r, k8 * 16, v);
  }
  __syncthreads();

  f32x4 acc[2][3];      // [rowtile][gate0=r, gate1=z, gate2=i_n]
  f32x4 accN[2];        // h_n
  f32x4 accL[2];        // emb-part logits (ms==0 only)
  const f32x4 zero = {0.f, 0.f, 0.f, 0.f};
#pragma unroll
  for (int rt = 0; rt < 2; ++rt) {
#pragma unroll
    for (int g = 0; g < 3; ++g) acc[rt][g] = zero;
    accN[rt] = zero;
    accL[rt] = zero;
  }

  // ---------------- GEMM1: X @ W_ih^T (B from LDS, depth-4 rotating A-prefetch) ----
  // during kc=12..15 the freed stages are refilled with the H rows for GEMM2
#pragma unroll
  for (int kc = 0; kc < EMB / 32; ++kc) {
    const int s = kc & 3;
    const short8 a0 = cvt8(pa[s][0], pb[s][0]);
    const short8 a1 = cvt8(pa[s][1], pb[s][1]);
    if (kc < 12) {
      pa[s][0] = *(const f32x4*)(x0 + (kc + 4) * 32); pb[s][0] = *(const f32x4*)(x0 + (kc + 4) * 32 + 4);
      pa[s][1] = *(const f32x4*)(x1 + (kc + 4) * 32); pb[s][1] = *(const f32x4*)(x1 + (kc + 4) * 32 + 4);
    } else {
      const int hk = kc - 12;
      pa[s][0] = *(const f32x4*)(h0 + hk * 32); pb[s][0] = *(const f32x4*)(h0 + hk * 32 + 4);
      pa[s][1] = *(const f32x4*)(h1 + hk * 32); pb[s][1] = *(const f32x4*)(h1 + hk * 32 + 4);
    }
    const int kb = (kc * 32 + lk * 8) * 2;
#pragma unroll
    for (int g = 0; g < 3; ++g) {
      const short8 bq = ldsW(sWih, EMB * 2, g * MSL + lr, kb);
      acc[0][g] = __builtin_amdgcn_mfma_f32_16x16x32_bf16(a0, bq, acc[0][g], 0, 0, 0);
      acc[1][g] = __builtin_amdgcn_mfma_f32_16x16x32_bf16(a1, bq, acc[1][g], 0, 0, 0);
    }
    if (ms0) {
      short8 bqL = {0, 0, 0, 0, 0, 0, 0, 0};
      if (lr < 2) bqL = ldsW(sWcl, EMB * 2, lr, kb);
      accL[0] = __builtin_amdgcn_mfma_f32_16x16x32_bf16(a0, bqL, accL[0], 0, 0, 0);
      accL[1] = __builtin_amdgcn_mfma_f32_16x16x32_bf16(a1, bqL, accL[1], 0, 0, 0);
    }
  }

  // ---------------- GEMM2: H @ W_hh^T (A already in stages 0..3) ----------------
#pragma unroll
  for (int kc = 0; kc < MEM / 32; ++kc) {
    const short8 a0 = cvt8(pa[kc][0], pb[kc][0]);
    const short8 a1 = cvt8(pa[kc][1], pb[kc][1]);
    const int kb = (kc * 32 + lk * 8) * 2;
    const short8 b0 = ldsW(sWhh, MEM * 2, 0 * MSL + lr, kb);
    const short8 b1 = ldsW(sWhh, MEM * 2, 1 * MSL + lr, kb);
    const short8 b2 = ldsW(sWhh, MEM * 2, 2 * MSL + lr, kb);
    acc[0][0] = __builtin_amdgcn_mfma_f32_16x16x32_bf16(a0, b0, acc[0][0], 0, 0, 0);
    acc[1][0] = __builtin_amdgcn_mfma_f32_16x16x32_bf16(a1, b0, acc[1][0], 0, 0, 0);
    acc[0][1] = __builtin_amdgcn_mfma_f32_16x16x32_bf16(a0, b1, acc[0][1], 0, 0, 0);
    acc[1][1] = __builtin_amdgcn_mfma_f32_16x16x32_bf16(a1, b1, acc[1][1], 0, 0, 0);
    accN[0]   = __builtin_amdgcn_mfma_f32_16x16x32_bf16(a0, b2, accN[0],   0, 0, 0);
    accN[1]   = __builtin_amdgcn_mfma_f32_16x16x32_bf16(a1, b2, accN[1],   0, 0, 0);
  }

  // ---------------- GRU epilogue: batch gid/hp loads, then math ----------------
  int   gidv[8];
  float hpv[8];
#pragma unroll
  for (int rt = 0; rt < 2; ++rt)
#pragma unroll
    for (int j = 0; j < 4; ++j) {
      const int q = rt * 4 + j;
      const int gid = __shfl(rt ? gid1 : gid0, lk * 4 + j);
      gidv[q] = gid;
      hpv[q] = bank[(size_t)gid * MEM + m];
    }

#pragma unroll
  for (int rt = 0; rt < 2; ++rt) {
#pragma unroll
    for (int j = 0; j < 4; ++j) {
      const int q    = rt * 4 + j;
      const int rowl = wrow + rt * 16 + lk * 4 + j;   // C/D: row=(lane>>4)*4+reg, col=lane&15
      const int grow = r0 + rowl;
      const bool valid = grow < N;
      const int gid = gidv[q];
      const float rg_ = sigm(acc[rt][0][j] + bir);
      const float zg  = sigm(acc[rt][1][j] + biz);
      const float hn  = accN[rt][j] + bhn;
      const float ng  = tanhfast(acc[rt][2][j] + bin_ + rg_ * hn);
      const float nv  = (1.f - zg) * ng + zg * hpv[q];
      if (valid) out_bank[(size_t)gid * MEM + m] = nv;
      float lp0 = nv * wcm0;
      float lp1 = nv * wcm1;
#pragma unroll
      for (int s = 1; s < 16; s <<= 1) {
        lp0 += __shfl_xor(lp0, s);
        lp1 += __shfl_xor(lp1, s);
      }
      if (valid && lr == 0) {
        if constexpr (PARTIALS) {
          part[(size_t)ms * 2 * N + (size_t)grow * 2 + 0] = lp0;
          part[(size_t)ms * 2 * N + (size_t)grow * 2 + 1] = lp1;
        } else {
          atomicAdd(out_logits + (size_t)grow * 2 + 0, lp0);
          atomicAdd(out_logits + (size_t)grow * 2 + 1, lp1);
        }
      }
      if (ms0 && valid && lr < 2) {
        if constexpr (PARTIALS) {
          part[(size_t)MSPLIT * 2 * N + (size_t)grow * 2 + lr] = accL[rt][j];
        } else {
          atomicAdd(out_logits + (size_t)grow * 2 + lr, accL[rt][j] + bcls[lr]);
        }
      }
    }
  }
}

extern "C" void kernel_launch(void* const* d_in, const int* in_sizes, int n_in,
                              void* d_out, int out_size, void* d_ws, size_t ws_size,
                              hipStream_t stream) {
  const float* emb  = (const float*)d_in[0];
  const int*   ids  = (const int*)d_in[1];
  const float* bank = (const float*)d_in[2];
  const float* wih  = (const float*)d_in[3];
  const float* whh  = (const float*)d_in[4];
  const float* bih  = (const float*)d_in[5];
  const float* bhh  = (const float*)d_in[6];
  const float* wcls = (const float*)d_in[7];
  const float* bcls = (const float*)d_in[8];

  const int N          = in_sizes[1];
  const int bank_elems = in_sizes[2];
  const int bank_rows  = bank_elems / MEM;
  const int n4         = bank_elems / 4;

  float* out_logits = (float*)d_out;
  float* out_bank   = (float*)d_out + (size_t)N * 2;

  const int wtot = G3 * EMB + G3 * MEM + 2 * CLS_K;
  const size_t wbytes   = (size_t)wtot * sizeof(short);          // 494080
  const size_t bmbytes  = ((size_t)bank_rows + 15) & ~15ull;
  const size_t partbytes = (size_t)NSLICE * 2 * N * sizeof(float);

  const bool haveW    = ws_size >= wbytes;
  const bool haveBM   = ws_size >= wbytes + bmbytes;
  const bool havePART = ws_size >= wbytes + bmbytes + partbytes;

  short* wb = (short*)d_ws;
  unsigned char* bm = (unsigned char*)d_ws + wbytes;
  float* part = (float*)((char*)d_ws + wbytes + bmbytes);

  // 1) weights -> bf16 (and zero logits only if atomic fallback)
  if (haveW)
    prep_w_kernel<<<(wtot + 255) / 256, 256, 0, stream>>>(wih, whh, wcls, wb);
  if (!havePART)
    zero_kernel<<<(N * 2 + 255) / 256, 256, 0, stream>>>(out_logits, N * 2);

  // 2) fused GRU (scatter + logit partials)
  const int nrb = (N + BR - 1) / BR;
  const int nb  = nrb * MSPLIT;
  if (haveW) {
    if (havePART)
      fused_gru_kernel<true, true><<<nb, NTHR, 0, stream>>>(emb, ids, bank, wih, whh, bih, bhh,
                                                            wcls, bcls, wb, part,
                                                            out_logits, out_bank, N);
    else
      fused_gru_kernel<true, false><<<nb, NTHR, 0, stream>>>(emb, ids, bank, wih, whh, bih, bhh,
                                                             wcls, bcls, wb, part,
                                                             out_logits, out_bank, N);
  } else {
    if (havePART)
      fused_gru_kernel<false, true><<<nb, NTHR, 0, stream>>>(emb, ids, bank, wih, whh, bih, bhh,
                                                             wcls, bcls, nullptr, part,
                                                             out_logits, out_bank, N);
    else
      fused_gru_kernel<false, false><<<nb, NTHR, 0, stream>>>(emb, ids, bank, wih, whh, bih, bhh,
                                                              wcls, bcls, nullptr, part,
                                                              out_logits, out_bank, N);
  }

  // 3) logit reduce (overlaps bank-copy region of the stream program order)
  if (havePART) {
    const int n2 = N * 2;
    reduce_logits_kernel<<<(n2 + 255) / 256, 256, 0, stream>>>(part, bcls, out_logits, n2);
  }

  // 4) bitmap + copy of non-active bank rows (disjoint from scatter rows)
  if (haveBM) {
    hipMemsetAsync(bm, 0, bmbytes, stream);
    bitmap_set_kernel<<<(N + 255) / 256, 256, 0, stream>>>(ids, bm, N);
    copy_bank_kernel<<<4096, 256, 0, stream>>>((const f32x4*)bank, (f32x4*)out_bank, bm, n4);
  } else {
    copy_bank_kernel<<<4096, 256, 0, stream>>>((const f32x4*)bank, (f32x4*)out_bank, nullptr, n4);
  }
}

// Round 8
// 305.870 us; speedup vs baseline: 1.8748x; 1.8748x over previous
//
#include <hip/hip_runtime.h>
#include <hip/hip_bf16.h>

typedef short short8 __attribute__((ext_vector_type(8)));
typedef float f32x4  __attribute__((ext_vector_type(4)));

#define EMB   512
#define MEM   128
#define G3    384
#define CLS_K 640
#define KJ    640            // joint K = EMB + MEM
#define BK    32             // K per step
#define NKS   20             // K-steps
#define ROWS  64             // rows per block
#define NTHR  512            // 8 waves
#define WB_CLS (G3 * KJ)     // cls table offset in wb (shorts)

__device__ __forceinline__ short f2b(float f) {
  __hip_bfloat16 h = __float2bfloat16(f);
  return __builtin_bit_cast(short, h);
}
__device__ __forceinline__ short8 cvt8(f32x4 a, f32x4 b) {
  short8 v;
  v[0] = f2b(a[0]); v[1] = f2b(a[1]); v[2] = f2b(a[2]); v[3] = f2b(a[3]);
  v[4] = f2b(b[0]); v[5] = f2b(b[1]); v[6] = f2b(b[2]); v[7] = f2b(b[3]);
  return v;
}
__device__ __forceinline__ float sigm(float x)     { return 1.f / (1.f + __expf(-x)); }
__device__ __forceinline__ float tanhfast(float x) { return 2.f / (1.f + __expf(-2.f * x)) - 1.f; }

// async global->LDS, 16B per lane; lds dest must be wave-uniform (HW adds lane*16)
__device__ __forceinline__ void gll16(const void* gsrc, void* ldst) {
  __builtin_amdgcn_global_load_lds(
      (const __attribute__((address_space(1))) unsigned int*)gsrc,
      (__attribute__((address_space(3))) unsigned int*)ldst, 16, 0, 0);
}

// ---- prep: unified bf16 weight table wb[col][640] = [W_ih | W_hh], + cls emb rows ----
__global__ void prep_w_kernel(const float* __restrict__ wih, const float* __restrict__ whh,
                              const float* __restrict__ wcls, short* __restrict__ outw) {
  int i = blockIdx.x * blockDim.x + threadIdx.x;
  const int nJ = G3 * KJ;
  const int nTot = nJ + 2 * EMB;
  if (i < nJ) {
    const int col = i / KJ, k = i - col * KJ;
    const float v = (k < EMB) ? wih[(size_t)col * EMB + k] : whh[(size_t)col * MEM + (k - EMB)];
    outw[i] = f2b(v);
  } else if (i < nTot) {
    const int j = i - nJ;
    const int r = j >> 9, k = j & 511;
    outw[i] = f2b(wcls[(size_t)r * CLS_K + k]);
  }
}

__global__ void bitmap_set_kernel(const int* __restrict__ ids, unsigned char* __restrict__ bm, int n) {
  int i = blockIdx.x * blockDim.x + threadIdx.x;
  if (i < n) bm[ids[i]] = 1;
}

__global__ void copy_bank_kernel(const f32x4* __restrict__ src, f32x4* __restrict__ dst,
                                 const unsigned char* __restrict__ bm, int n4) {
  int i = blockIdx.x * blockDim.x + threadIdx.x;
  int stride = gridDim.x * blockDim.x;
  for (; i < n4; i += stride) {
    if (bm && bm[i >> 5]) continue;
    dst[i] = src[i];
  }
}

template <bool BF16W>
__global__ __launch_bounds__(NTHR, 4)
void fused_gru_kernel(const float* __restrict__ emb, const int* __restrict__ ids,
                      const float* __restrict__ bank,
                      const float* __restrict__ Wihf, const float* __restrict__ Whhf,
                      const float* __restrict__ bih,  const float* __restrict__ bhh,
                      const float* __restrict__ Wcls, const float* __restrict__ bcls,
                      const short* __restrict__ Wb,
                      float* __restrict__ out_logits, float* __restrict__ out_bank, int N) {
  __shared__ __align__(16) float sA[2][ROWS * BK];   // fp32 A tile, 16KB
  __shared__ __align__(16) short sB[2][G3 * BK];     // bf16 B tile, 48KB
  __shared__ __align__(16) short sCls[2 * EMB];      // cls emb rows, 2KB

  const int t    = threadIdx.x;
  const int lane = t & 63;
  const int w    = t >> 6;        // 0..7
  const int wr   = w & 3;         // row group (16 rows)
  const int wc   = w >> 2;        // m half (64 m-cols)
  const int lr   = lane & 15;
  const int lk   = lane >> 4;
  const int r0   = blockIdx.x * ROWS;

  // ---- per-lane staging sources (pre-swizzled: slot c holds data chunk c^((c>>3)&7)) ----
  const int rowS = w * 8 + (lane >> 3);
  const int schS = (lane & 7) ^ (rowS & 7);
  int growS = r0 + rowS; if (growS > N - 1) growS = N - 1;
  const int gidS = ids[growS];
  const char* pEmbS  = (const char*)(emb  + (size_t)growS * EMB) + schS * 16;
  const char* pBankS = (const char*)(bank + (size_t)gidS  * MEM) + schS * 16;

  int bOff[3];
#pragma unroll
  for (int s = 0; s < 3; ++s) {
    const int cB = s * 512 + w * 64 + lane;
    const int cp = cB ^ ((cB >> 3) & 7);
    bOff[s] = (cp >> 2) * KJ + (cp & 3) * 8;   // shorts
  }

  // ---- cls table -> LDS (linear) ----
  if (t < 128) {
    short8 v;
    if constexpr (BF16W) v = *(const short8*)(Wb + WB_CLS + t * 8);
    else {
      const int r = t >> 6, k = (t & 63) * 8;
      const float* p = Wcls + (size_t)r * CLS_K + k;
      v = cvt8(*(const f32x4*)p, *(const f32x4*)(p + 4));
    }
    *(short8*)(sCls + t * 8) = v;
  }

  // ---- staging of one K-step into buf ----
  auto STAGE = [&](int kc, int buf) {
    const char* srcA = (kc < 16) ? (pEmbS + kc * 128) : (pBankS + (kc - 16) * 128);
    gll16(srcA, (char*)&sA[buf][0] + w * 1024);
    if constexpr (BF16W) {
      const short* wbk = Wb + kc * BK;
#pragma unroll
      for (int s = 0; s < 3; ++s)
        gll16((const void*)(wbk + bOff[s]), (char*)&sB[buf][0] + (s * 512 + w * 64) * 16);
    } else {
#pragma unroll
      for (int s = 0; s < 3; ++s) {
        const int g = s * 512 + w * 64 + lane;     // data chunk
        const int col = g >> 2, kch = g & 3;
        const int k = kc * BK + kch * 8;
        short8 v;
        if (k < EMB) { const float* p = Wihf + (size_t)col * EMB + k;         v = cvt8(*(const f32x4*)p, *(const f32x4*)(p + 4)); }
        else         { const float* p = Whhf + (size_t)col * MEM + (k - EMB); v = cvt8(*(const f32x4*)p, *(const f32x4*)(p + 4)); }
        *(short8*)((char*)&sB[buf][0] + (g ^ ((g >> 3) & 7)) * 16) = v;
      }
    }
  };

  STAGE(0, 0);
  __syncthreads();   // drain -> buf0 ready

  f32x4 accR[4], accZ[4], accIN[4], accHN[4], accL;
  const f32x4 zero = {0.f, 0.f, 0.f, 0.f};
#pragma unroll
  for (int mt = 0; mt < 4; ++mt) { accR[mt] = zero; accZ[mt] = zero; accIN[mt] = zero; accHN[mt] = zero; }
  accL = zero;

  for (int kc = 0; kc < NKS; ++kc) {
    const int buf = kc & 1;
    if (kc < NKS - 1) STAGE(kc + 1, buf ^ 1);

    // A fragment: row = wr*16+lr, k-chunk = lk (8 fp32 -> bf16)
    const int rowA = wr * 16 + lr;
    const int ab   = rowA * 128 + lk * 32;
    const int sw   = (rowA & 7) << 4;
    const char* ap = (const char*)&sA[buf][0];
    const f32x4 av0 = *(const f32x4*)(ap + ((ab)      ^ sw));
    const f32x4 av1 = *(const f32x4*)(ap + ((ab + 16) ^ sw));
    const short8 af = cvt8(av0, av1);

    const char* bp = (const char*)&sB[buf][0];
#pragma unroll
    for (int mt = 0; mt < 4; ++mt) {
#pragma unroll
      for (int g = 0; g < 3; ++g) {
        const int col = (g * 8 + wc * 4 + mt) * 16 + lr;
        const int bb  = col * 64 + lk * 16;
        const short8 bf = *(const short8*)(bp + (bb ^ (((bb >> 7) & 7) << 4)));
        if (g == 0)      accR[mt] = __builtin_amdgcn_mfma_f32_16x16x32_bf16(af, bf, accR[mt], 0, 0, 0);
        else if (g == 1) accZ[mt] = __builtin_amdgcn_mfma_f32_16x16x32_bf16(af, bf, accZ[mt], 0, 0, 0);
        else {
          if (kc < 16) accIN[mt] = __builtin_amdgcn_mfma_f32_16x16x32_bf16(af, bf, accIN[mt], 0, 0, 0);
          else         accHN[mt] = __builtin_amdgcn_mfma_f32_16x16x32_bf16(af, bf, accHN[mt], 0, 0, 0);
        }
      }
    }
    if (wc == 0 && kc < 16) {
      short8 bqL = {0, 0, 0, 0, 0, 0, 0, 0};
      if (lr < 2) bqL = *(const short8*)(sCls + lr * 512 + kc * 32 + lk * 8);
      accL = __builtin_amdgcn_mfma_f32_16x16x32_bf16(af, bqL, accL, 0, 0, 0);
    }
    __syncthreads();   // next buf staged; this buf consumed
  }

  // ---------------- epilogue: GRU + scatter + logits (all in-block) ----------------
  const int wrow = wr * 16;
  float* sLPp = &sA[0][0];          // [2][64][2] logit mem-part partials (sA reuse)
  float* sLEp = &sA[0][0] + 256;    // [64][2] emb-part

  float bir[4], biz[4], bin_[4], bhn[4], wcm0[4], wcm1[4];
#pragma unroll
  for (int mt = 0; mt < 4; ++mt) {
    const int m = wc * 64 + mt * 16 + lr;
    bir[mt]  = bih[m] + bhh[m];
    biz[mt]  = bih[MEM + m] + bhh[MEM + m];
    bin_[mt] = bih[2 * MEM + m];
    bhn[mt]  = bhh[2 * MEM + m];
    wcm0[mt] = Wcls[EMB + m];
    wcm1[mt] = Wcls[CLS_K + EMB + m];
  }

  int  gidE[4]; bool valE[4];
#pragma unroll
  for (int j = 0; j < 4; ++j) {
    int gr = r0 + wrow + lk * 4 + j;
    valE[j] = gr < N; if (gr > N - 1) gr = N - 1;
    gidE[j] = ids[gr];
  }
  float hp[4][4];
#pragma unroll
  for (int j = 0; j < 4; ++j)
#pragma unroll
    for (int mt = 0; mt < 4; ++mt)
      hp[j][mt] = bank[(size_t)gidE[j] * MEM + wc * 64 + mt * 16 + lr];

#pragma unroll
  for (int j = 0; j < 4; ++j) {
    float lp0 = 0.f, lp1 = 0.f;
#pragma unroll
    for (int mt = 0; mt < 4; ++mt) {
      const int m = wc * 64 + mt * 16 + lr;
      const float rg = sigm(accR[mt][j] + bir[mt]);
      const float zg = sigm(accZ[mt][j] + biz[mt]);
      const float ng = tanhfast(accIN[mt][j] + bin_[mt] + rg * (accHN[mt][j] + bhn[mt]));
      const float nv = (1.f - zg) * ng + zg * hp[j][mt];
      if (valE[j]) out_bank[(size_t)gidE[j] * MEM + m] = nv;
      lp0 += nv * wcm0[mt];
      lp1 += nv * wcm1[mt];
    }
#pragma unroll
    for (int s = 1; s < 16; s <<= 1) {
      lp0 += __shfl_xor(lp0, s);
      lp1 += __shfl_xor(lp1, s);
    }
    const int row = wrow + lk * 4 + j;
    if (lr == 0) { sLPp[(wc * 64 + row) * 2 + 0] = lp0; sLPp[(wc * 64 + row) * 2 + 1] = lp1; }
    if (wc == 0 && lr < 2) sLEp[row * 2 + lr] = accL[j];
  }
  __syncthreads();

  if (t < 128) {
    const int row = t >> 1, c = t & 1;
    const int gr = r0 + row;
    if (gr < N)
      out_logits[(size_t)gr * 2 + c] =
          sLEp[row * 2 + c] + sLPp[row * 2 + c] + sLPp[(64 + row) * 2 + c] + bcls[c];
  }
}

extern "C" void kernel_launch(void* const* d_in, const int* in_sizes, int n_in,
                              void* d_out, int out_size, void* d_ws, size_t ws_size,
                              hipStream_t stream) {
  const float* emb  = (const float*)d_in[0];
  const int*   ids  = (const int*)d_in[1];
  const float* bank = (const float*)d_in[2];
  const float* wih  = (const float*)d_in[3];
  const float* whh  = (const float*)d_in[4];
  const float* bih  = (const float*)d_in[5];
  const float* bhh  = (const float*)d_in[6];
  const float* wcls = (const float*)d_in[7];
  const float* bcls = (const float*)d_in[8];

  const int N          = in_sizes[1];
  const int bank_elems = in_sizes[2];
  const int bank_rows  = bank_elems / MEM;
  const int n4         = bank_elems / 4;

  float* out_logits = (float*)d_out;
  float* out_bank   = (float*)d_out + (size_t)N * 2;

  const int wtot = G3 * KJ + 2 * EMB;                 // 246784 shorts
  const size_t wbytes  = (size_t)wtot * sizeof(short);
  const size_t bmbytes = ((size_t)bank_rows + 15) & ~15ull;

  const bool haveW  = ws_size >= wbytes;
  const bool haveBM = ws_size >= wbytes + bmbytes;

  short* wb = (short*)d_ws;
  unsigned char* bm = (unsigned char*)d_ws + wbytes;

  // 1) weight prep (bf16, joint-K layout)
  if (haveW)
    prep_w_kernel<<<(wtot + 255) / 256, 256, 0, stream>>>(wih, whh, wcls, wb);

  // 2) fused joint-K GEMM + GRU + scatter + logits
  const int nb = (N + ROWS - 1) / ROWS;
  if (haveW)
    fused_gru_kernel<true><<<nb, NTHR, 0, stream>>>(emb, ids, bank, wih, whh, bih, bhh,
                                                    wcls, bcls, wb, out_logits, out_bank, N);
  else
    fused_gru_kernel<false><<<nb, NTHR, 0, stream>>>(emb, ids, bank, wih, whh, bih, bhh,
                                                     wcls, bcls, nullptr, out_logits, out_bank, N);

  // 3) copy of non-active bank rows (disjoint from scatter rows; overlaps tail)
  if (haveBM) {
    hipMemsetAsync(bm, 0, bmbytes, stream);
    bitmap_set_kernel<<<(N + 255) / 256, 256, 0, stream>>>(ids, bm, N);
    copy_bank_kernel<<<4096, 256, 0, stream>>>((const f32x4*)bank, (f32x4*)out_bank, bm, n4);
  } else {
    copy_bank_kernel<<<4096, 256, 0, stream>>>((const f32x4*)bank, (f32x4*)out_bank, nullptr, n4);
  }
}